// Round 1
// baseline (288.562 us; speedup 1.0000x reference)
//
#include <hip/hip_runtime.h>
#include <math.h>

#define IC_   2048
#define NC_   16
#define OD_   16
#define ID_   8
#define B_    128
#define CH_   16            // chunks over IC
#define ICPB_ (IC_/CH_)     // 128 i per block
#define NW_   4             // waves per block (256 threads)
#define LOG2E_ 1.4426950408889634f

// One routing pass: recompute u_hat[b,i,c,o] on the fly, weight by softmax(dot(u, v_scaled))
// over c, accumulate partial s into s_part[(b*CH+ch)*256 + co].
// Lane layout: per (b,i) one wave owns all 256 (c,o); lane l holds co = l + 64k,
// i.e. o = l&15, c = (l>>4) + 4k for k=0..3.
template<bool UNIFORM>
__global__ __launch_bounds__(256)
void caps_pass(const float* __restrict__ x, const float* __restrict__ W,
               const float* __restrict__ vs, float* __restrict__ s_part) {
  const int b    = blockIdx.x;
  const int ch   = blockIdx.y;
  const int tid  = threadIdx.x;
  const int wid  = tid >> 6;
  const int lane = tid & 63;

  // per-lane v (pre-scaled by log2 e): vreg[k] = vs[b*256 + lane + 64k]
  float vr0 = 0.f, vr1 = 0.f, vr2 = 0.f, vr3 = 0.f;
  if (!UNIFORM) {
    const float* vsb = vs + b * (NC_ * OD_);
    vr0 = vsb[lane];
    vr1 = vsb[lane + 64];
    vr2 = vsb[lane + 128];
    vr3 = vsb[lane + 192];
  }

  float a0 = 0.f, a1 = 0.f, a2 = 0.f, a3 = 0.f;

  const float* xb    = x + (size_t)b * IC_ * ID_;
  const int    ibase = ch * ICPB_;

  for (int t = 0; t < ICPB_ / NW_; ++t) {
    const int i = ibase + t * NW_ + wid;

    const float4 x0 = *(const float4*)(xb + i * ID_);
    const float4 x1 = *(const float4*)(xb + i * ID_ + 4);

    const float* wr = W + (size_t)i * (NC_ * OD_ * ID_) + lane * ID_;

    float4 w0, w1;
    float  u0, u1, u2, u3;
    w0 = *(const float4*)(wr);
    w1 = *(const float4*)(wr + 4);
    u0 = w0.x*x0.x + w0.y*x0.y + w0.z*x0.z + w0.w*x0.w
       + w1.x*x1.x + w1.y*x1.y + w1.z*x1.z + w1.w*x1.w;
    w0 = *(const float4*)(wr + 64*ID_);
    w1 = *(const float4*)(wr + 64*ID_ + 4);
    u1 = w0.x*x0.x + w0.y*x0.y + w0.z*x0.z + w0.w*x0.w
       + w1.x*x1.x + w1.y*x1.y + w1.z*x1.z + w1.w*x1.w;
    w0 = *(const float4*)(wr + 128*ID_);
    w1 = *(const float4*)(wr + 128*ID_ + 4);
    u2 = w0.x*x0.x + w0.y*x0.y + w0.z*x0.z + w0.w*x0.w
       + w1.x*x1.x + w1.y*x1.y + w1.z*x1.z + w1.w*x1.w;
    w0 = *(const float4*)(wr + 192*ID_);
    w1 = *(const float4*)(wr + 192*ID_ + 4);
    u3 = w0.x*x0.x + w0.y*x0.y + w0.z*x0.z + w0.w*x0.w
       + w1.x*x1.x + w1.y*x1.y + w1.z*x1.z + w1.w*x1.w;

    if (UNIFORM) {
      // softmax(0) = 1/16 uniform; the 1/16 is applied in the reduce kernel.
      a0 += u0; a1 += u1; a2 += u2; a3 += u3;
    } else {
      // logits d[c] = sum_o u[c,o] * v_scaled[c,o]  (reduce over the 16-lane o-group)
      float d0 = u0 * vr0, d1 = u1 * vr1, d2 = u2 * vr2, d3 = u3 * vr3;
#pragma unroll
      for (int m = 1; m <= 8; m <<= 1) {
        d0 += __shfl_xor(d0, m);
        d1 += __shfl_xor(d1, m);
        d2 += __shfl_xor(d2, m);
        d3 += __shfl_xor(d3, m);
      }
      // softmax over all 16 c (no max-subtract: |logit| ~ 1e-2, overflow impossible)
      const float e0 = __builtin_amdgcn_exp2f(d0);
      const float e1 = __builtin_amdgcn_exp2f(d1);
      const float e2 = __builtin_amdgcn_exp2f(d2);
      const float e3 = __builtin_amdgcn_exp2f(d3);
      float Z = (e0 + e1) + (e2 + e3);      // this lane's 4 c's (one per group-of-4)
      Z += __shfl_xor(Z, 16);               // combine across the 4 c-groups
      Z += __shfl_xor(Z, 32);
      const float r = __builtin_amdgcn_rcpf(Z);
      a0 += e0 * r * u0;
      a1 += e1 * r * u1;
      a2 += e2 * r * u2;
      a3 += e3 * r * u3;
    }
  }

  // reduce the 4 waves' partials in LDS, write one 256-float partial per block
  __shared__ float red[NW_][NC_ * OD_];
  red[wid][lane]       = a0;
  red[wid][lane + 64]  = a1;
  red[wid][lane + 128] = a2;
  red[wid][lane + 192] = a3;
  __syncthreads();
  const float p = red[0][tid] + red[1][tid] + red[2][tid] + red[3][tid];
  s_part[((size_t)b * CH_ + ch) * (NC_ * OD_) + tid] = p;
}

// Reduce partials over CH chunks, squash, and produce v / scaled-v / final output.
// mode 0: after pass 1 -> vraw = v1, vs_next = v1*log2e          (scale = 1/16)
// mode 1: after pass 2 -> vs_next = (v1 + v2)*log2e              (scale = 1)
// mode 2: after pass 3 -> out = v3                               (scale = 1)
__global__ __launch_bounds__(256)
void caps_reduce(const float* __restrict__ s_part, float* __restrict__ vraw,
                 float* __restrict__ vs_next, float* __restrict__ out,
                 const float* __restrict__ v_prev_raw, float scale, int mode) {
  const int b = blockIdx.x;
  const int t = threadIdx.x;   // t = co = c*16 + o

  float s = 0.f;
#pragma unroll
  for (int ch = 0; ch < CH_; ++ch)
    s += s_part[((size_t)b * CH_ + ch) * (NC_ * OD_) + t];
  s *= scale;

  // squash: sq = |s_c|^2 over o (16-lane group)
  float sq = s * s;
  sq += __shfl_xor(sq, 1);
  sq += __shfl_xor(sq, 2);
  sq += __shfl_xor(sq, 4);
  sq += __shfl_xor(sq, 8);
  const float f = sq / ((1.f + sq) * sqrtf(sq + 1e-8f));
  const float v = s * f;

  if (mode == 0) {
    vraw[b * 256 + t]    = v;
    vs_next[b * 256 + t] = v * LOG2E_;
  } else if (mode == 1) {
    vs_next[b * 256 + t] = (v + v_prev_raw[b * 256 + t]) * LOG2E_;
  } else {
    out[b * 256 + t] = v;
  }
}

extern "C" void kernel_launch(void* const* d_in, const int* in_sizes, int n_in,
                              void* d_out, int out_size, void* d_ws, size_t ws_size,
                              hipStream_t stream) {
  (void)in_sizes; (void)n_in; (void)out_size; (void)ws_size;

  const float* x = (const float*)d_in[0];
  const float* W = (const float*)d_in[1];
  float* out = (float*)d_out;

  float* s_part = (float*)d_ws;                          // B*CH*256 floats = 2 MB
  float* v1raw  = s_part + (size_t)B_ * CH_ * NC_ * OD_; // 128 KB
  float* vs     = v1raw + (size_t)B_ * NC_ * OD_;        // 128 KB

  const dim3 gridP(B_, CH_), blk(256), gridR(B_);

  // pass 1 (uniform weights)
  caps_pass<true><<<gridP, blk, 0, stream>>>(x, W, nullptr, s_part);
  caps_reduce<<<gridR, blk, 0, stream>>>(s_part, v1raw, vs, nullptr, nullptr, 1.f / 16.f, 0);
  // pass 2
  caps_pass<false><<<gridP, blk, 0, stream>>>(x, W, vs, s_part);
  caps_reduce<<<gridR, blk, 0, stream>>>(s_part, nullptr, vs, nullptr, v1raw, 1.f, 1);
  // pass 3
  caps_pass<false><<<gridP, blk, 0, stream>>>(x, W, vs, s_part);
  caps_reduce<<<gridR, blk, 0, stream>>>(s_part, nullptr, nullptr, out, nullptr, 1.f, 2);
}